// Round 3
// baseline (643.538 us; speedup 1.0000x reference)
//
#include <hip/hip_runtime.h>
#include <hip/hip_bf16.h>
#include <stdint.h>

#define B_ 8
#define T_ 2048
#define E_ 1024
#define H_ 1024
#define M_ (B_*T_)   // 16384

typedef __attribute__((ext_vector_type(8))) short bf16x8;
typedef __attribute__((ext_vector_type(4))) float f32x4;

__device__ __forceinline__ unsigned short f2bf(float f) {
  union { float f; unsigned int u; } v; v.f = f;
  unsigned int u = v.u;
  unsigned int r = u + 0x7fffu + ((u >> 16) & 1u);   // RNE (inputs finite)
  return (unsigned short)(r >> 16);
}

// ---------- convert x (fp32) -> xb (bf16), 8 elems / thread ----------
__global__ void conv_x_kernel(const float* __restrict__ x,
                              unsigned short* __restrict__ xb, int n8) {
  int i = blockIdx.x * blockDim.x + threadIdx.x;
  if (i >= n8) return;
  const float4* src = (const float4*)(x + (size_t)i * 8);
  float4 a = src[0], b = src[1];
  uint4 o;
  o.x = (unsigned)f2bf(a.x) | ((unsigned)f2bf(a.y) << 16);
  o.y = (unsigned)f2bf(a.z) | ((unsigned)f2bf(a.w) << 16);
  o.z = (unsigned)f2bf(b.x) | ((unsigned)f2bf(b.y) << 16);
  o.w = (unsigned)f2bf(b.z) | ((unsigned)f2bf(b.w) << 16);
  *(uint4*)(xb + (size_t)i * 8) = o;
}

// ---------- convert + transpose W (E x H fp32) -> wT (H x E bf16) ----------
__global__ void conv_wT_kernel(const float* __restrict__ W0, const float* __restrict__ W1,
                               const float* __restrict__ W2,
                               unsigned short* __restrict__ T0, unsigned short* __restrict__ T1,
                               unsigned short* __restrict__ T2) {
  __shared__ float tile[32][33];
  const float* W = (blockIdx.z == 0) ? W0 : (blockIdx.z == 1) ? W1 : W2;
  unsigned short* Tt = (blockIdx.z == 0) ? T0 : (blockIdx.z == 1) ? T1 : T2;
  int k0 = blockIdx.x * 32;
  int n0 = blockIdx.y * 32;
  int t = threadIdx.x;
#pragma unroll
  for (int i = 0; i < 4; ++i) {
    int e = t + i * 256; int r = e >> 5, c = e & 31;
    tile[r][c] = W[(size_t)(k0 + r) * H_ + n0 + c];
  }
  __syncthreads();
#pragma unroll
  for (int i = 0; i < 4; ++i) {
    int e = t + i * 256; int r = e >> 5, c = e & 31;   // r = n-local, c = k-local
    Tt[(size_t)(n0 + r) * E_ + k0 + c] = f2bf(tile[c][r]);
  }
}

// ---------- fused QKV GEMM: out = xb @ wT^T + bias ----------
// 128x128 tile, BK=64, 4 waves (2x2 of 64x64), mfma_f32_16x16x32_bf16
// V (which==2) is written TRANSPOSED: vT[d][m], packed 8B stores.
__global__ __launch_bounds__(256)
void gemm_qkv_kernel(const unsigned short* __restrict__ xb,
                     const unsigned short* __restrict__ wqT, const unsigned short* __restrict__ wkT,
                     const unsigned short* __restrict__ wvT,
                     const float* __restrict__ bq, const float* __restrict__ bk,
                     const float* __restrict__ bv,
                     unsigned short* __restrict__ qb, unsigned short* __restrict__ kb,
                     unsigned short* __restrict__ vb) {
  __shared__ short Alds[128 * 72];   // stride 72 elems = 144B (16B-aligned, 2-way-free banks)
  __shared__ short Blds[128 * 72];
  int which = blockIdx.y >> 3;
  int ncol0 = (blockIdx.y & 7) * 128;
  const unsigned short* Bt = (which == 0) ? wqT : (which == 1) ? wkT : wvT;
  const float* bias = (which == 0) ? bq : (which == 1) ? bk : bv;
  unsigned short* outp = (which == 0) ? qb : (which == 1) ? kb : vb;
  int m0 = blockIdx.x * 128;
  int tid = threadIdx.x, lane = tid & 63, wid = tid >> 6;
  int wm = (wid >> 1) * 64, wn = (wid & 1) * 64;

  f32x4 acc[4][4];
#pragma unroll
  for (int i = 0; i < 4; ++i)
#pragma unroll
    for (int j = 0; j < 4; ++j)
#pragma unroll
      for (int r = 0; r < 4; ++r) acc[i][j][r] = 0.f;

  for (int kb0 = 0; kb0 < E_; kb0 += 64) {
#pragma unroll
    for (int i = 0; i < 4; ++i) {
      int c = tid + i * 256;
      int row = c >> 3, k8 = (c & 7) * 8;
      *(uint4*)&Alds[row * 72 + k8] = *(const uint4*)(xb + (size_t)(m0 + row) * E_ + kb0 + k8);
      *(uint4*)&Blds[row * 72 + k8] = *(const uint4*)(Bt + (size_t)(ncol0 + row) * E_ + kb0 + k8);
    }
    __syncthreads();
#pragma unroll
    for (int kt = 0; kt < 2; ++kt) {
      bf16x8 af[4], bfr[4];
#pragma unroll
      for (int mt = 0; mt < 4; ++mt)
        af[mt] = *(const bf16x8*)&Alds[(wm + mt * 16 + (lane & 15)) * 72 + kt * 32 + (lane >> 4) * 8];
#pragma unroll
      for (int nt = 0; nt < 4; ++nt)
        bfr[nt] = *(const bf16x8*)&Blds[(wn + nt * 16 + (lane & 15)) * 72 + kt * 32 + (lane >> 4) * 8];
#pragma unroll
      for (int mt = 0; mt < 4; ++mt)
#pragma unroll
        for (int nt = 0; nt < 4; ++nt)
          acc[mt][nt] = __builtin_amdgcn_mfma_f32_16x16x32_bf16(af[mt], bfr[nt], acc[mt][nt], 0, 0, 0);
    }
    __syncthreads();
  }
  if (which == 2) {
    // transposed write: vT[d = gcol][m = grow..grow+3], 8B packed
#pragma unroll
    for (int nt = 0; nt < 4; ++nt) {
      int gcol = ncol0 + wn + nt * 16 + (lane & 15);
      float bb = bias[gcol];
#pragma unroll
      for (int mt = 0; mt < 4; ++mt) {
        int grow = m0 + wm + mt * 16 + (lane >> 4) * 4;
        ushort4 o;
        o.x = f2bf(acc[mt][nt][0] + bb);
        o.y = f2bf(acc[mt][nt][1] + bb);
        o.z = f2bf(acc[mt][nt][2] + bb);
        o.w = f2bf(acc[mt][nt][3] + bb);
        *(ushort4*)(outp + (size_t)gcol * M_ + grow) = o;
      }
    }
  } else {
#pragma unroll
    for (int nt = 0; nt < 4; ++nt) {
      int gcol = ncol0 + wn + nt * 16 + (lane & 15);
      float bb = bias[gcol];
#pragma unroll
      for (int mt = 0; mt < 4; ++mt) {
        int grow = m0 + wm + mt * 16 + (lane >> 4) * 4;
#pragma unroll
        for (int r = 0; r < 4; ++r)
          outp[(size_t)(grow + r) * H_ + gcol] = f2bf(acc[mt][nt][r] + bb);
      }
    }
  }
}

// ---------- flash attention, causal, D=1024 ----------
// 8 waves/block. Per 256-key chunk: wave w computes full-D S chunk [32q x 32keys]
// (keys k0+w*32..), so no cross-wave S reduction. PV: wave w owns D-slice w*128.
// Q tile (32x1024 bf16) in swizzled LDS; P (32x256 bf16) in swizzled LDS.
// Deep register pipelines: K 8-deep, V 2-deep, to hide L2 latency at 2 waves/SIMD.
__global__ __launch_bounds__(512, 2)
void attn_kernel(const unsigned short* __restrict__ qg, const unsigned short* __restrict__ kg,
                 const unsigned short* __restrict__ vT, float* __restrict__ out) {
  __shared__ char Qlds[32 * 2048];      // 64KB, row stride 2048B, swz ^((row&7)<<4)
  __shared__ char Plds[32 * 512];       // 16KB, row stride 512B,  swz ^((row&7)<<4)
  __shared__ float wred[32 * 16];       // [row][0..7]=max part, [8..15]=sum part, swz ^(((row>>2)&3)<<4)

  const int bid = blockIdx.x;
  const int b = bid & 7, pj = bid >> 3;       // batch fastest -> same batch per XCD (heuristic)
  const size_t bT = (size_t)b * T_;
  const int tid = threadIdx.x, lane = tid & 63, w = tid >> 6;
  const int hi = lane >> 4, lo = lane & 15;
  const int ds = w * 128;

  for (int phase = 0; phase < 2; ++phase) {
    const int qt = (phase == 0) ? pj : 63 - pj;
    const int q0 = qt * 32;

    // ---- stage Q tile (32 x 1024), swizzled ----
    for (int e = tid; e < 4096; e += 512) {
      int row = e >> 7, c16 = e & 127;
      uint4 v = *(const uint4*)(qg + (bT + q0 + row) * (size_t)H_ + c16 * 8);
      int byte = (row << 11) | (c16 << 4);
      *(uint4*)(Qlds + (byte ^ ((row & 7) << 4))) = v;
    }

    float m_run[2][4], l_run[2][4];
    f32x4 oacc[2][8];
#pragma unroll
    for (int mt = 0; mt < 2; ++mt) {
#pragma unroll
      for (int r = 0; r < 4; ++r) { m_run[mt][r] = -1e30f; l_run[mt][r] = 0.f; }
#pragma unroll
      for (int nt = 0; nt < 8; ++nt)
#pragma unroll
        for (int r = 0; r < 4; ++r) oacc[mt][nt][r] = 0.f;
    }
    __syncthreads();   // Q staged

    const int nkb = (qt >> 3) + 1;
    for (int kbi = 0; kbi < nkb; ++kbi) {
      const int k0 = kbi << 8;
      const int kw = k0 + w * 32;              // this wave's key base
      const bool active = kw <= q0 + 31;       // wave-uniform

      // ---- QK^T: full-D S chunk [32 x 32] for this wave's keys ----
      f32x4 sacc[2][2];
#pragma unroll
      for (int i = 0; i < 2; ++i)
#pragma unroll
        for (int j = 0; j < 2; ++j)
#pragma unroll
          for (int r = 0; r < 4; ++r) sacc[i][j][r] = 0.f;

      if (active) {
        const unsigned short* kp = kg + (bT + kw + lo) * (size_t)H_ + hi * 8;
        const int qb0 = (lo << 11) | (hi << 4);
        const int qb1 = ((16 + lo) << 11) | (hi << 4);
        const int qswz = (lo & 7) << 4;
        // 8-deep rolling K pipeline: 16 b128 loads in flight
        bf16x8 kq0[8], kq1[8];
#pragma unroll
        for (int i = 0; i < 8; ++i) {
          kq0[i] = *(const bf16x8*)(kp + i * 32);
          kq1[i] = *(const bf16x8*)(kp + 16 * H_ + i * 32);
        }
#pragma unroll
        for (int kt = 0; kt < 32; ++kt) {
          bf16x8 k0f = kq0[kt & 7], k1f = kq1[kt & 7];
          if (kt < 24) {
            kq0[kt & 7] = *(const bf16x8*)(kp + (kt + 8) * 32);
            kq1[kt & 7] = *(const bf16x8*)(kp + 16 * H_ + (kt + 8) * 32);
          }
          bf16x8 a0 = *(const bf16x8*)(Qlds + ((qb0 + (kt << 6)) ^ qswz));
          bf16x8 a1 = *(const bf16x8*)(Qlds + ((qb1 + (kt << 6)) ^ qswz));
          __builtin_amdgcn_s_setprio(1);
          sacc[0][0] = __builtin_amdgcn_mfma_f32_16x16x32_bf16(a0, k0f, sacc[0][0], 0, 0, 0);
          sacc[0][1] = __builtin_amdgcn_mfma_f32_16x16x32_bf16(a0, k1f, sacc[0][1], 0, 0, 0);
          sacc[1][0] = __builtin_amdgcn_mfma_f32_16x16x32_bf16(a1, k0f, sacc[1][0], 0, 0, 0);
          sacc[1][1] = __builtin_amdgcn_mfma_f32_16x16x32_bf16(a1, k1f, sacc[1][1], 0, 0, 0);
          __builtin_amdgcn_s_setprio(0);
        }
      }

      // ---- masked scale + wave-partial rowmax ----
      float sm[2][2][4];
      float pm[2][4];
#pragma unroll
      for (int mt = 0; mt < 2; ++mt)
#pragma unroll
        for (int r = 0; r < 4; ++r) {
          const int gq = q0 + mt * 16 + hi * 4 + r;
          float v0 = (active && (kw + lo) <= gq)      ? sacc[mt][0][r] * 0.03125f : -1e30f;
          float v1 = (active && (kw + 16 + lo) <= gq) ? sacc[mt][1][r] * 0.03125f : -1e30f;
          sm[mt][0][r] = v0; sm[mt][1][r] = v1;
          pm[mt][r] = fmaxf(v0, v1);
        }
#pragma unroll
      for (int msk = 1; msk <= 8; msk <<= 1)
#pragma unroll
        for (int mt = 0; mt < 2; ++mt)
#pragma unroll
          for (int r = 0; r < 4; ++r)
            pm[mt][r] = fmaxf(pm[mt][r], __shfl_xor(pm[mt][r], msk));
      if (lo == 0) {
#pragma unroll
        for (int mt = 0; mt < 2; ++mt)
#pragma unroll
          for (int r = 0; r < 4; ++r) {
            int row = mt * 16 + hi * 4 + r;
            int byte = (row << 6) | (w << 2);
            *(float*)((char*)wred + (byte ^ (((row >> 2) & 3) << 4))) = pm[mt][r];
          }
      }
      __syncthreads();   // B1: wmax partials ready

      // ---- global row max, p = exp(s - m), write P, partial row sums ----
      float mn[2][4], ps[2][4];
#pragma unroll
      for (int mt = 0; mt < 2; ++mt)
#pragma unroll
        for (int r = 0; r < 4; ++r) {
          const int row = mt * 16 + hi * 4 + r;
          const int base = row << 6;
          const int wsz = ((row >> 2) & 3) << 4;
          float4 w0 = *(const float4*)((char*)wred + ((base + 0) ^ wsz));
          float4 w1 = *(const float4*)((char*)wred + ((base + 16) ^ wsz));
          float mx = fmaxf(fmaxf(fmaxf(w0.x, w0.y), fmaxf(w0.z, w0.w)),
                           fmaxf(fmaxf(w1.x, w1.y), fmaxf(w1.z, w1.w)));
          float m2 = fmaxf(m_run[mt][r], mx);
          mn[mt][r] = m2;
          float p0 = __expf(sm[mt][0][r] - m2);
          float p1 = __expf(sm[mt][1][r] - m2);
          const int pswz = (row & 7) << 4;
          const int pb = (row << 9) | (w << 6) | (lo << 1);
          *(unsigned short*)(Plds + (pb ^ pswz)) = f2bf(p0);
          *(unsigned short*)(Plds + ((pb | 32) ^ pswz)) = f2bf(p1);
          ps[mt][r] = p0 + p1;
        }
#pragma unroll
      for (int msk = 1; msk <= 8; msk <<= 1)
#pragma unroll
        for (int mt = 0; mt < 2; ++mt)
#pragma unroll
          for (int r = 0; r < 4; ++r)
            ps[mt][r] += __shfl_xor(ps[mt][r], msk);
      if (lo == 0) {
#pragma unroll
        for (int mt = 0; mt < 2; ++mt)
#pragma unroll
          for (int r = 0; r < 4; ++r) {
            int row = mt * 16 + hi * 4 + r;
            int byte = (row << 6) | ((8 + w) << 2);
            *(float*)((char*)wred + (byte ^ (((row >> 2) & 3) << 4))) = ps[mt][r];
          }
      }
      __syncthreads();   // B2: P + sum partials ready

      // ---- l/m update + O rescale ----
#pragma unroll
      for (int mt = 0; mt < 2; ++mt)
#pragma unroll
        for (int r = 0; r < 4; ++r) {
          const int row = mt * 16 + hi * 4 + r;
          const int base = row << 6;
          const int wsz = ((row >> 2) & 3) << 4;
          float4 s0 = *(const float4*)((char*)wred + ((base + 32) ^ wsz));
          float4 s1 = *(const float4*)((char*)wred + ((base + 48) ^ wsz));
          float lsum = (s0.x + s0.y) + (s0.z + s0.w) + (s1.x + s1.y) + (s1.z + s1.w);
          float a = __expf(m_run[mt][r] - mn[mt][r]);
          m_run[mt][r] = mn[mt][r];
          l_run[mt][r] = l_run[mt][r] * a + lsum;
#pragma unroll
          for (int nt = 0; nt < 8; ++nt) oacc[mt][nt][r] *= a;
        }

      // ---- PV: wave's D-slice [ds, ds+128), K-dim = 256 keys, V 2-deep pipeline ----
      const unsigned short* vp = vT + bT + k0 + hi * 8;
      bf16x8 vf0[8], vf1[8];
#pragma unroll
      for (int nt = 0; nt < 8; ++nt) {
        const unsigned short* q = vp + (size_t)(ds + nt * 16 + lo) * M_;
        vf0[nt] = *(const bf16x8*)(q);
        vf1[nt] = *(const bf16x8*)(q + 32);
      }
      const int pb0 = (lo << 9) | (hi << 4);
      const int pb1 = ((16 + lo) << 9) | (hi << 4);
      const int pswz = (lo & 7) << 4;
#pragma unroll
      for (int kt = 0; kt < 8; ++kt) {
        bf16x8 cv[8];
#pragma unroll
        for (int nt = 0; nt < 8; ++nt) cv[nt] = (kt & 1) ? vf1[nt] : vf0[nt];
        if (kt < 6) {
#pragma unroll
          for (int nt = 0; nt < 8; ++nt) {
            const unsigned short* q = vp + (size_t)(ds + nt * 16 + lo) * M_ + (kt + 2) * 32;
            if (kt & 1) vf1[nt] = *(const bf16x8*)q; else vf0[nt] = *(const bf16x8*)q;
          }
        }
        bf16x8 p0 = *(const bf16x8*)(Plds + ((pb0 + (kt << 6)) ^ pswz));
        bf16x8 p1 = *(const bf16x8*)(Plds + ((pb1 + (kt << 6)) ^ pswz));
        __builtin_amdgcn_s_setprio(1);
#pragma unroll
        for (int nt = 0; nt < 8; ++nt) {
          oacc[0][nt] = __builtin_amdgcn_mfma_f32_16x16x32_bf16(p0, cv[nt], oacc[0][nt], 0, 0, 0);
          oacc[1][nt] = __builtin_amdgcn_mfma_f32_16x16x32_bf16(p1, cv[nt], oacc[1][nt], 0, 0, 0);
        }
        __builtin_amdgcn_s_setprio(0);
      }
      __syncthreads();   // B3: PV done -> next iter may overwrite P/wred
    }

    // ---- epilogue: O / l ----
#pragma unroll
    for (int mt = 0; mt < 2; ++mt)
#pragma unroll
      for (int r = 0; r < 4; ++r) {
        float li = 1.0f / l_run[mt][r];
        const size_t rb = (bT + q0 + mt * 16 + hi * 4 + r) * (size_t)H_ + ds + lo;
#pragma unroll
        for (int nt = 0; nt < 8; ++nt)
          out[rb + nt * 16] = oacc[mt][nt][r] * li;
      }
  }
}

extern "C" void kernel_launch(void* const* d_in, const int* in_sizes, int n_in,
                              void* d_out, int out_size, void* d_ws, size_t ws_size,
                              hipStream_t stream) {
  const float* x  = (const float*)d_in[0];
  const float* Wq = (const float*)d_in[1];
  const float* bq = (const float*)d_in[2];
  const float* Wk = (const float*)d_in[3];
  const float* bk = (const float*)d_in[4];
  const float* Wv = (const float*)d_in[5];
  const float* bv = (const float*)d_in[6];
  float* out = (float*)d_out;

  unsigned short* ws = (unsigned short*)d_ws;
  unsigned short* xb  = ws;                              // M x E bf16
  unsigned short* wqT = xb  + (size_t)M_ * E_;           // H x E bf16 (transposed)
  unsigned short* wkT = wqT + (size_t)E_ * H_;
  unsigned short* wvT = wkT + (size_t)E_ * H_;
  unsigned short* qb  = wvT + (size_t)E_ * H_;           // M x H bf16
  unsigned short* kbp = qb  + (size_t)M_ * H_;
  unsigned short* vTp = kbp + (size_t)M_ * H_;           // H x M bf16 (V transposed)

  conv_x_kernel<<<(M_ * E_ / 8 + 255) / 256, 256, 0, stream>>>(x, xb, M_ * E_ / 8);
  conv_wT_kernel<<<dim3(32, 32, 3), 256, 0, stream>>>(Wq, Wk, Wv, wqT, wkT, wvT);
  gemm_qkv_kernel<<<dim3(128, 24), 256, 0, stream>>>(xb, wqT, wkT, wvT, bq, bk, bv, qb, kbp, vTp);
  attn_kernel<<<dim3(256), 512, 0, stream>>>(qb, kbp, vTp, out);
}

// Round 4
// 300.932 us; speedup vs baseline: 2.1385x; 2.1385x over previous
//
#include <hip/hip_runtime.h>
#include <hip/hip_bf16.h>
#include <stdint.h>

#define B_ 8
#define T_ 2048
#define E_ 1024
#define H_ 1024
#define M_ (B_*T_)   // 16384

typedef __attribute__((ext_vector_type(8))) short bf16x8;
typedef __attribute__((ext_vector_type(4))) float f32x4;

__device__ __forceinline__ unsigned short f2bf(float f) {
  union { float f; unsigned int u; } v; v.f = f;
  unsigned int u = v.u;
  unsigned int r = u + 0x7fffu + ((u >> 16) & 1u);   // RNE (inputs finite)
  return (unsigned short)(r >> 16);
}

__device__ __forceinline__ float bf2f(unsigned short s) {
  union { unsigned int u; float f; } v; v.u = ((unsigned int)s) << 16;
  return v.f;
}

// ---------- convert x (fp32) -> xb (bf16), 8 elems / thread ----------
__global__ void conv_x_kernel(const float* __restrict__ x,
                              unsigned short* __restrict__ xb, int n8) {
  int i = blockIdx.x * blockDim.x + threadIdx.x;
  if (i >= n8) return;
  const float4* src = (const float4*)(x + (size_t)i * 8);
  float4 a = src[0], b = src[1];
  uint4 o;
  o.x = (unsigned)f2bf(a.x) | ((unsigned)f2bf(a.y) << 16);
  o.y = (unsigned)f2bf(a.z) | ((unsigned)f2bf(a.w) << 16);
  o.z = (unsigned)f2bf(b.x) | ((unsigned)f2bf(b.y) << 16);
  o.w = (unsigned)f2bf(b.z) | ((unsigned)f2bf(b.w) << 16);
  *(uint4*)(xb + (size_t)i * 8) = o;
}

// ---------- convert + transpose W (E x H fp32) -> wT (H x E bf16) ----------
__global__ void conv_wT_kernel(const float* __restrict__ W0, const float* __restrict__ W1,
                               const float* __restrict__ W2,
                               unsigned short* __restrict__ T0, unsigned short* __restrict__ T1,
                               unsigned short* __restrict__ T2) {
  __shared__ float tile[32][33];
  const float* W = (blockIdx.z == 0) ? W0 : (blockIdx.z == 1) ? W1 : W2;
  unsigned short* Tt = (blockIdx.z == 0) ? T0 : (blockIdx.z == 1) ? T1 : T2;
  int k0 = blockIdx.x * 32;
  int n0 = blockIdx.y * 32;
  int t = threadIdx.x;
#pragma unroll
  for (int i = 0; i < 4; ++i) {
    int e = t + i * 256; int r = e >> 5, c = e & 31;
    tile[r][c] = W[(size_t)(k0 + r) * H_ + n0 + c];
  }
  __syncthreads();
#pragma unroll
  for (int i = 0; i < 4; ++i) {
    int e = t + i * 256; int r = e >> 5, c = e & 31;   // r = n-local, c = k-local
    Tt[(size_t)(n0 + r) * E_ + k0 + c] = f2bf(tile[c][r]);
  }
}

// ---------- fused QKV GEMM: out = xb @ wT^T + bias ----------
// 128x128 tile, BK=64, 4 waves (2x2 of 64x64), mfma_f32_16x16x32_bf16
// V (which==2) is written TRANSPOSED: vT[d][m], packed 8B stores.
__global__ __launch_bounds__(256)
void gemm_qkv_kernel(const unsigned short* __restrict__ xb,
                     const unsigned short* __restrict__ wqT, const unsigned short* __restrict__ wkT,
                     const unsigned short* __restrict__ wvT,
                     const float* __restrict__ bq, const float* __restrict__ bk,
                     const float* __restrict__ bv,
                     unsigned short* __restrict__ qb, unsigned short* __restrict__ kb,
                     unsigned short* __restrict__ vb) {
  __shared__ short Alds[128 * 72];   // stride 72 elems = 144B (16B-aligned, 2-way-free banks)
  __shared__ short Blds[128 * 72];
  int which = blockIdx.y >> 3;
  int ncol0 = (blockIdx.y & 7) * 128;
  const unsigned short* Bt = (which == 0) ? wqT : (which == 1) ? wkT : wvT;
  const float* bias = (which == 0) ? bq : (which == 1) ? bk : bv;
  unsigned short* outp = (which == 0) ? qb : (which == 1) ? kb : vb;
  int m0 = blockIdx.x * 128;
  int tid = threadIdx.x, lane = tid & 63, wid = tid >> 6;
  int wm = (wid >> 1) * 64, wn = (wid & 1) * 64;

  f32x4 acc[4][4];
#pragma unroll
  for (int i = 0; i < 4; ++i)
#pragma unroll
    for (int j = 0; j < 4; ++j)
#pragma unroll
      for (int r = 0; r < 4; ++r) acc[i][j][r] = 0.f;

  for (int kb0 = 0; kb0 < E_; kb0 += 64) {
#pragma unroll
    for (int i = 0; i < 4; ++i) {
      int c = tid + i * 256;
      int row = c >> 3, k8 = (c & 7) * 8;
      *(uint4*)&Alds[row * 72 + k8] = *(const uint4*)(xb + (size_t)(m0 + row) * E_ + kb0 + k8);
      *(uint4*)&Blds[row * 72 + k8] = *(const uint4*)(Bt + (size_t)(ncol0 + row) * E_ + kb0 + k8);
    }
    __syncthreads();
#pragma unroll
    for (int kt = 0; kt < 2; ++kt) {
      bf16x8 af[4], bfr[4];
#pragma unroll
      for (int mt = 0; mt < 4; ++mt)
        af[mt] = *(const bf16x8*)&Alds[(wm + mt * 16 + (lane & 15)) * 72 + kt * 32 + (lane >> 4) * 8];
#pragma unroll
      for (int nt = 0; nt < 4; ++nt)
        bfr[nt] = *(const bf16x8*)&Blds[(wn + nt * 16 + (lane & 15)) * 72 + kt * 32 + (lane >> 4) * 8];
#pragma unroll
      for (int mt = 0; mt < 4; ++mt)
#pragma unroll
        for (int nt = 0; nt < 4; ++nt)
          acc[mt][nt] = __builtin_amdgcn_mfma_f32_16x16x32_bf16(af[mt], bfr[nt], acc[mt][nt], 0, 0, 0);
    }
    __syncthreads();
  }
  if (which == 2) {
    // transposed write: vT[d = gcol][m = grow..grow+3], 8B packed
#pragma unroll
    for (int nt = 0; nt < 4; ++nt) {
      int gcol = ncol0 + wn + nt * 16 + (lane & 15);
      float bb = bias[gcol];
#pragma unroll
      for (int mt = 0; mt < 4; ++mt) {
        int grow = m0 + wm + mt * 16 + (lane >> 4) * 4;
        ushort4 o;
        o.x = f2bf(acc[mt][nt][0] + bb);
        o.y = f2bf(acc[mt][nt][1] + bb);
        o.z = f2bf(acc[mt][nt][2] + bb);
        o.w = f2bf(acc[mt][nt][3] + bb);
        *(ushort4*)(outp + (size_t)gcol * M_ + grow) = o;
      }
    }
  } else {
#pragma unroll
    for (int nt = 0; nt < 4; ++nt) {
      int gcol = ncol0 + wn + nt * 16 + (lane & 15);
      float bb = bias[gcol];
#pragma unroll
      for (int mt = 0; mt < 4; ++mt) {
        int grow = m0 + wm + mt * 16 + (lane >> 4) * 4;
#pragma unroll
        for (int r = 0; r < 4; ++r)
          outp[(size_t)(grow + r) * H_ + gcol] = f2bf(acc[mt][nt][r] + bb);
      }
    }
  }
}

// ---------- S = (Q K^T) * scale, causal lower-tri 128x128 tiles, bf16 out ----------
__global__ __launch_bounds__(256)
void sgemm_kernel(const unsigned short* __restrict__ qb, const unsigned short* __restrict__ kb,
                  unsigned short* __restrict__ S) {
  __shared__ short Alds[128 * 72];
  __shared__ short Blds[128 * 72];
  int id = blockIdx.x;
  int b = id & 7, t = id >> 3;            // batch-fastest: same batch -> same XCD
  int mb = 0;
  while ((mb + 1) * (mb + 2) / 2 <= t) ++mb;
  int nb = t - mb * (mb + 1) / 2;         // nb <= mb (lower triangle)
  const size_t bT = (size_t)b * T_;
  const unsigned short* Ap = qb + (bT + mb * 128) * (size_t)H_;
  const unsigned short* Bp = kb + (bT + nb * 128) * (size_t)H_;
  int tid = threadIdx.x, lane = tid & 63, wid = tid >> 6;
  int wm = (wid >> 1) * 64, wn = (wid & 1) * 64;

  f32x4 acc[4][4];
#pragma unroll
  for (int i = 0; i < 4; ++i)
#pragma unroll
    for (int j = 0; j < 4; ++j)
#pragma unroll
      for (int r = 0; r < 4; ++r) acc[i][j][r] = 0.f;

  for (int kb0 = 0; kb0 < H_; kb0 += 64) {
#pragma unroll
    for (int i = 0; i < 4; ++i) {
      int c = tid + i * 256;
      int row = c >> 3, k8 = (c & 7) * 8;
      *(uint4*)&Alds[row * 72 + k8] = *(const uint4*)(Ap + (size_t)row * H_ + kb0 + k8);
      *(uint4*)&Blds[row * 72 + k8] = *(const uint4*)(Bp + (size_t)row * H_ + kb0 + k8);
    }
    __syncthreads();
#pragma unroll
    for (int kt = 0; kt < 2; ++kt) {
      bf16x8 af[4], bfr[4];
#pragma unroll
      for (int mt = 0; mt < 4; ++mt)
        af[mt] = *(const bf16x8*)&Alds[(wm + mt * 16 + (lane & 15)) * 72 + kt * 32 + (lane >> 4) * 8];
#pragma unroll
      for (int nt = 0; nt < 4; ++nt)
        bfr[nt] = *(const bf16x8*)&Blds[(wn + nt * 16 + (lane & 15)) * 72 + kt * 32 + (lane >> 4) * 8];
#pragma unroll
      for (int mt = 0; mt < 4; ++mt)
#pragma unroll
        for (int nt = 0; nt < 4; ++nt)
          acc[mt][nt] = __builtin_amdgcn_mfma_f32_16x16x32_bf16(af[mt], bfr[nt], acc[mt][nt], 0, 0, 0);
    }
    __syncthreads();
  }
#pragma unroll
  for (int nt = 0; nt < 4; ++nt) {
    int gcol = nb * 128 + wn + nt * 16 + (lane & 15);
#pragma unroll
    for (int mt = 0; mt < 4; ++mt) {
      int grow = mb * 128 + wm + mt * 16 + (lane >> 4) * 4;
#pragma unroll
      for (int r = 0; r < 4; ++r)
        S[(bT + grow + r) * (size_t)T_ + gcol] = f2bf(acc[mt][nt][r] * 0.03125f);
    }
  }
}

// ---------- in-place causal row softmax: S(bf16 scores) -> P(bf16 probs) ----------
// one wave per row; lane covers 32 cols as 4 x bf16x8 strided segments
__global__ __launch_bounds__(256)
void smax_kernel(unsigned short* __restrict__ S) {
  int id = blockIdx.x;
  int b = id & 7, rb = id >> 3;                 // rb 0..511
  int w = threadIdx.x >> 6, lane = threadIdx.x & 63;
  int row = rb * 4 + w;
  unsigned short* rp = S + ((size_t)b * T_ + row) * T_;

  bf16x8 d[4];
#pragma unroll
  for (int j = 0; j < 4; ++j)
    d[j] = *(const bf16x8*)(rp + j * 512 + lane * 8);

  float v[32];
  float mx = -1e30f;
#pragma unroll
  for (int j = 0; j < 4; ++j)
#pragma unroll
    for (int e = 0; e < 8; ++e) {
      int col = j * 512 + lane * 8 + e;
      float f = bf2f((unsigned short)d[j][e]);
      f = (col <= row) ? f : -1e30f;
      v[j * 8 + e] = f;
      mx = fmaxf(mx, f);
    }
#pragma unroll
  for (int msk = 1; msk <= 32; msk <<= 1) mx = fmaxf(mx, __shfl_xor(mx, msk));

  float s = 0.f;
#pragma unroll
  for (int i = 0; i < 32; ++i) {
    v[i] = __expf(v[i] - mx);                   // masked: exp(-1e30 - mx) underflows to 0
    s += v[i];
  }
#pragma unroll
  for (int msk = 1; msk <= 32; msk <<= 1) s += __shfl_xor(s, msk);
  float inv = 1.0f / s;

#pragma unroll
  for (int j = 0; j < 4; ++j) {
    bf16x8 o;
#pragma unroll
    for (int e = 0; e < 8; ++e) o[e] = (short)f2bf(v[j * 8 + e] * inv);
    *(bf16x8*)(rp + j * 512 + lane * 8) = o;
  }
}

// ---------- O = P V, causal (K-range = (mb+1)*128), fp32 out ----------
__global__ __launch_bounds__(256)
void pv_kernel(const unsigned short* __restrict__ P, const unsigned short* __restrict__ vT,
               float* __restrict__ out) {
  __shared__ short Alds[128 * 72];
  __shared__ short Blds[128 * 72];
  int id = blockIdx.x;
  int b = id & 7, u = id >> 3;
  int mb = 15 - (u >> 3);                  // biggest K-range first (load balance)
  int nb = u & 7;                          // d-block 0..7
  const size_t bT = (size_t)b * T_;
  const unsigned short* Ap = P + (bT + mb * 128) * (size_t)T_;          // row stride T_
  const unsigned short* Bp = vT + (size_t)(nb * 128) * M_ + bT;         // row stride M_
  int tid = threadIdx.x, lane = tid & 63, wid = tid >> 6;
  int wm = (wid >> 1) * 64, wn = (wid & 1) * 64;

  f32x4 acc[4][4];
#pragma unroll
  for (int i = 0; i < 4; ++i)
#pragma unroll
    for (int j = 0; j < 4; ++j)
#pragma unroll
      for (int r = 0; r < 4; ++r) acc[i][j][r] = 0.f;

  const int kmax = (mb + 1) * 128;
  for (int kb0 = 0; kb0 < kmax; kb0 += 64) {
#pragma unroll
    for (int i = 0; i < 4; ++i) {
      int c = tid + i * 256;
      int row = c >> 3, k8 = (c & 7) * 8;
      *(uint4*)&Alds[row * 72 + k8] = *(const uint4*)(Ap + (size_t)row * T_ + kb0 + k8);
      *(uint4*)&Blds[row * 72 + k8] = *(const uint4*)(Bp + (size_t)row * M_ + kb0 + k8);
    }
    __syncthreads();
#pragma unroll
    for (int kt = 0; kt < 2; ++kt) {
      bf16x8 af[4], bfr[4];
#pragma unroll
      for (int mt = 0; mt < 4; ++mt)
        af[mt] = *(const bf16x8*)&Alds[(wm + mt * 16 + (lane & 15)) * 72 + kt * 32 + (lane >> 4) * 8];
#pragma unroll
      for (int nt = 0; nt < 4; ++nt)
        bfr[nt] = *(const bf16x8*)&Blds[(wn + nt * 16 + (lane & 15)) * 72 + kt * 32 + (lane >> 4) * 8];
#pragma unroll
      for (int mt = 0; mt < 4; ++mt)
#pragma unroll
        for (int nt = 0; nt < 4; ++nt)
          acc[mt][nt] = __builtin_amdgcn_mfma_f32_16x16x32_bf16(af[mt], bfr[nt], acc[mt][nt], 0, 0, 0);
    }
    __syncthreads();
  }
#pragma unroll
  for (int nt = 0; nt < 4; ++nt) {
    int gcol = nb * 128 + wn + nt * 16 + (lane & 15);
#pragma unroll
    for (int mt = 0; mt < 4; ++mt) {
      int grow = mb * 128 + wm + mt * 16 + (lane >> 4) * 4;
#pragma unroll
      for (int r = 0; r < 4; ++r)
        out[(bT + grow + r) * (size_t)H_ + gcol] = acc[mt][nt][r];
    }
  }
}

extern "C" void kernel_launch(void* const* d_in, const int* in_sizes, int n_in,
                              void* d_out, int out_size, void* d_ws, size_t ws_size,
                              hipStream_t stream) {
  const float* x  = (const float*)d_in[0];
  const float* Wq = (const float*)d_in[1];
  const float* bq = (const float*)d_in[2];
  const float* Wk = (const float*)d_in[3];
  const float* bk = (const float*)d_in[4];
  const float* Wv = (const float*)d_in[5];
  const float* bv = (const float*)d_in[6];
  float* out = (float*)d_out;

  unsigned short* ws = (unsigned short*)d_ws;
  unsigned short* xb  = ws;                              // M x E bf16      (32MB)
  unsigned short* wqT = xb  + (size_t)M_ * E_;           // H x E bf16
  unsigned short* wkT = wqT + (size_t)E_ * H_;
  unsigned short* wvT = wkT + (size_t)E_ * H_;
  unsigned short* qb  = wvT + (size_t)E_ * H_;           // M x H bf16      (32MB)
  unsigned short* kbp = qb  + (size_t)M_ * H_;           // M x H bf16
  unsigned short* vTp = kbp + (size_t)M_ * H_;           // H x M bf16 (V transposed)
  unsigned short* Sp  = vTp + (size_t)M_ * H_;           // B x T x T bf16  (67MB) S, then P in-place

  conv_x_kernel<<<(M_ * E_ / 8 + 255) / 256, 256, 0, stream>>>(x, xb, M_ * E_ / 8);
  conv_wT_kernel<<<dim3(32, 32, 3), 256, 0, stream>>>(Wq, Wk, Wv, wqT, wkT, wvT);
  gemm_qkv_kernel<<<dim3(128, 24), 256, 0, stream>>>(xb, wqT, wkT, wvT, bq, bk, bv, qb, kbp, vTp);
  sgemm_kernel<<<dim3(136 * 8), 256, 0, stream>>>(qb, kbp, Sp);
  smax_kernel<<<dim3(512 * 8), 256, 0, stream>>>(Sp);
  pv_kernel<<<dim3(128 * 8), 256, 0, stream>>>(Sp, vTp, out);
}